// Round 2
// baseline (9392.838 us; speedup 1.0000x reference)
//
#include <hip/hip_runtime.h>
#include <hip/hip_bf16.h>
#include <stdint.h>

typedef unsigned long long u64;
typedef _Float16 f16x8 __attribute__((ext_vector_type(8)));
typedef float f32x4 __attribute__((ext_vector_type(4)));

#define V_   32000
#define D_   512
#define H_   512
#define B_   8
#define T_   512
#define BT_  4096
#define G4H_ 2048

static __device__ inline unsigned pack2h(_Float16 a, _Float16 b) {
  union { _Float16 h[2]; unsigned u; } p;
  p.h[0] = a; p.h[1] = b;
  return p.u;
}

// =====================================================================
// Generic 128x128-tile fp32 GEMM:  C = act(A @ B^T + bias)
//   MODE 0: A = emb_W[src[m]],  B=W_ih,     bias=b_ih+b_hh,        N=2048,K=512
//   MODE 1: A = hs,             B=attn1_W,  bias=attn1_b, tanh,    N=512, K=512
//   MODE 2: A = [ctx | hs],     B=concat_W, bias=concat_b, tanh -> fp16 out
// =====================================================================
template<int MODE>
__global__ __launch_bounds__(256)
void gemm128(const float* __restrict__ A1, const float* __restrict__ A2,
             const float* __restrict__ Bm, const float* __restrict__ bias,
             const float* __restrict__ bias2, const int* __restrict__ src,
             float* __restrict__ C, _Float16* __restrict__ Ch,
             int M, int N, int K)
{
  __shared__ float As[16][132];
  __shared__ float Bs[16][132];
  const int tid = threadIdx.x;
  const int bm = blockIdx.y * 128, bn = blockIdx.x * 128;
  const int tx = tid & 15, ty = tid >> 4;
  const int lr = tid >> 2, lk4 = tid & 3;

  int ga0 = 0, ga1 = 0;
  if constexpr (MODE == 0) { ga0 = src[bm + lr]; ga1 = src[bm + lr + 64]; }

  float acc[8][8];
  #pragma unroll
  for (int i = 0; i < 8; ++i)
    #pragma unroll
    for (int j = 0; j < 8; ++j) acc[i][j] = 0.f;

  for (int k0 = 0; k0 < K; k0 += 16) {
    const int ak = k0 + 4 * lk4;
    float4 av0, av1, bv0, bv1;
    if constexpr (MODE == 0) {
      av0 = *(const float4*)&A1[(long)ga0 * 512 + ak];
      av1 = *(const float4*)&A1[(long)ga1 * 512 + ak];
    } else if constexpr (MODE == 2) {
      if (ak < 512) {
        av0 = *(const float4*)&A1[(long)(bm + lr) * 512 + ak];
        av1 = *(const float4*)&A1[(long)(bm + lr + 64) * 512 + ak];
      } else {
        av0 = *(const float4*)&A2[(long)(bm + lr) * 512 + (ak - 512)];
        av1 = *(const float4*)&A2[(long)(bm + lr + 64) * 512 + (ak - 512)];
      }
    } else {
      av0 = *(const float4*)&A1[(long)(bm + lr) * K + ak];
      av1 = *(const float4*)&A1[(long)(bm + lr + 64) * K + ak];
    }
    bv0 = *(const float4*)&Bm[(long)(bn + lr) * K + ak];
    bv1 = *(const float4*)&Bm[(long)(bn + lr + 64) * K + ak];

    __syncthreads();
    As[4*lk4+0][lr]    = av0.x; As[4*lk4+1][lr]    = av0.y;
    As[4*lk4+2][lr]    = av0.z; As[4*lk4+3][lr]    = av0.w;
    As[4*lk4+0][lr+64] = av1.x; As[4*lk4+1][lr+64] = av1.y;
    As[4*lk4+2][lr+64] = av1.z; As[4*lk4+3][lr+64] = av1.w;
    Bs[4*lk4+0][lr]    = bv0.x; Bs[4*lk4+1][lr]    = bv0.y;
    Bs[4*lk4+2][lr]    = bv0.z; Bs[4*lk4+3][lr]    = bv0.w;
    Bs[4*lk4+0][lr+64] = bv1.x; Bs[4*lk4+1][lr+64] = bv1.y;
    Bs[4*lk4+2][lr+64] = bv1.z; Bs[4*lk4+3][lr+64] = bv1.w;
    __syncthreads();

    #pragma unroll
    for (int kk = 0; kk < 16; ++kk) {
      float4 a0 = *(float4*)&As[kk][ty * 8];
      float4 a1 = *(float4*)&As[kk][ty * 8 + 4];
      float4 b0 = *(float4*)&Bs[kk][tx * 4];
      float4 b1 = *(float4*)&Bs[kk][64 + tx * 4];
      float a[8] = {a0.x, a0.y, a0.z, a0.w, a1.x, a1.y, a1.z, a1.w};
      float b[8] = {b0.x, b0.y, b0.z, b0.w, b1.x, b1.y, b1.z, b1.w};
      #pragma unroll
      for (int i = 0; i < 8; ++i)
        #pragma unroll
        for (int j = 0; j < 8; ++j) acc[i][j] += a[i] * b[j];
    }
  }

  #pragma unroll
  for (int i = 0; i < 8; ++i) {
    const int m = bm + ty * 8 + i;
    #pragma unroll
    for (int half = 0; half < 2; ++half) {
      const int n0 = bn + half * 64 + tx * 4;
      float vv[4];
      #pragma unroll
      for (int j = 0; j < 4; ++j) {
        float x = acc[i][half * 4 + j];
        x += bias[n0 + j];
        if constexpr (MODE == 0) x += bias2[n0 + j];
        if constexpr (MODE == 1 || MODE == 2) x = tanhf(x);
        vv[j] = x;
      }
      if constexpr (MODE == 2) {
        #pragma unroll
        for (int j = 0; j < 4; ++j) Ch[(long)m * 512 + n0 + j] = (_Float16)vv[j];
      } else {
        *(float4*)&C[(long)m * N + n0] = *(float4*)vv;
      }
    }
  }
}

// =====================================================================
// Persistent LSTM, 128 WGs x 256 thr. WG owns h-dims [4wg,4wg+4) -> 16
// gate rows (order n = g*4 + d'). W_hh as f16 hi/lo MFMA B-fragments in
// registers. Sync per step: per-WG tag array + parity-double-buffered
// h slot transported via agent-scope u64 atomics.
// =====================================================================
__global__ __launch_bounds__(256)
void lstm_mfma(const float* __restrict__ A, const float* __restrict__ W_hh,
               float* __restrict__ hs, u64* __restrict__ hslot,
               unsigned* __restrict__ tags)
{
  __shared__ _Float16 hfrag[2][4096];   // [piece][(q*8+b)*8+j], q=k>>3, 16KB
  __shared__ float Cred[4 * 256];       // per-wave C partials
  __shared__ float gv[128];             // [m][n] 8x16 raw gates
  __shared__ float hvals[32];
  const int tid = threadIdx.x;
  const int wg  = blockIdx.x;
  const int d0  = wg * 4;
  const int wv  = tid >> 6, l = tid & 63;

  // --- W_hh fragments: lane l holds rows n=l&15 (grow), k-groups per kt ---
  const int nn = l & 15;
  const int grow = (nn >> 2) * 512 + d0 + (nn & 3);
  f16x8 w_hi[4], w_lo[4];
  #pragma unroll
  for (int i = 0; i < 4; ++i) {
    const int kt = wv * 4 + i;
    const int k0 = kt * 32 + (l >> 4) * 8;
    const float4 v0 = *(const float4*)&W_hh[(long)grow * 512 + k0];
    const float4 v1 = *(const float4*)&W_hh[(long)grow * 512 + k0 + 4];
    float vf[8] = {v0.x, v0.y, v0.z, v0.w, v1.x, v1.y, v1.z, v1.w};
    #pragma unroll
    for (int j = 0; j < 8; ++j) {
      _Float16 hi = (_Float16)vf[j];
      _Float16 lo = (_Float16)(vf[j] - (float)hi);
      w_hi[i][j] = hi; w_lo[i][j] = lo;
    }
  }

  for (int s = tid; s < 4096; s += 256) { hfrag[0][s] = (_Float16)0.f; hfrag[1][s] = (_Float16)0.f; }
  float c_reg = 0.f;
  const int pm = tid >> 4, pn = tid & 15;      // reduce-phase mapping (tid<128)
  const long arow = (long)(pn >> 2) * 512 + d0 + (pn & 3);
  __syncthreads();

  for (int t = 0; t < T_; ++t) {
    float a_val = 0.f;
    if (tid < 128) a_val = A[((long)pm * T_ + t) * G4H_ + arow];

    if (t > 0) {
      // ---- poll per-WG tags (one wave-instr per 64 tags) ----
      unsigned v0, v1;
      do {
        v0 = __hip_atomic_load(&tags[l],      __ATOMIC_RELAXED, __HIP_MEMORY_SCOPE_AGENT);
        v1 = __hip_atomic_load(&tags[64 + l], __ATOMIC_RELAXED, __HIP_MEMORY_SCOPE_AGENT);
      } while (!__all(v0 >= (unsigned)t && v1 >= (unsigned)t));
      __threadfence();
      // ---- bulk fetch h[t-1] from parity slot, split to f16 hi/lo ----
      const u64* src = (const u64*)(hslot + ((t - 1) & 1) * 2048);
      #pragma unroll
      for (int i = 0; i < 8; ++i) {
        const int u = i * 256 + tid;
        u64 pkt = __hip_atomic_load(&src[u], __ATOMIC_RELAXED, __HIP_MEMORY_SCOPE_AGENT);
        float f0 = __uint_as_float((unsigned)pkt);
        float f1 = __uint_as_float((unsigned)(pkt >> 32));
        _Float16 h0 = (_Float16)f0, h1 = (_Float16)f1;
        _Float16 l0 = (_Float16)(f0 - (float)h0), l1 = (_Float16)(f1 - (float)h1);
        *(unsigned*)&hfrag[0][2 * u] = pack2h(h0, h1);
        *(unsigned*)&hfrag[1][2 * u] = pack2h(l0, l1);
      }
    }
    __syncthreads();   // SYNC_A: h staged

    // ---- MFMA: this wave covers kt = wv*4 .. wv*4+3 ----
    f32x4 acc = {0.f, 0.f, 0.f, 0.f};
    #pragma unroll
    for (int i = 0; i < 4; ++i) {
      const int kt = wv * 4 + i;
      const int boff = ((kt * 4 + (l >> 4)) * 8 + (l & 7)) * 8;
      f16x8 ah = *(f16x8*)&hfrag[0][boff];
      f16x8 al = *(f16x8*)&hfrag[1][boff];
      acc = __builtin_amdgcn_mfma_f32_16x16x32_f16(ah, w_hi[i], acc, 0, 0, 0);
      acc = __builtin_amdgcn_mfma_f32_16x16x32_f16(al, w_hi[i], acc, 0, 0, 0);
      acc = __builtin_amdgcn_mfma_f32_16x16x32_f16(ah, w_lo[i], acc, 0, 0, 0);
    }
    *(f32x4*)&Cred[wv * 256 + l * 4] = acc;
    __syncthreads();   // SYNC_B

    if (tid < 128) {   // reduce k-split partials + input-gate part
      const int lane = 16 * (pm >> 2) + pn, reg = pm & 3;
      float g = a_val;
      #pragma unroll
      for (int w = 0; w < 4; ++w) g += Cred[w * 256 + lane * 4 + reg];
      gv[pm * 16 + pn] = g;
    }
    __syncthreads();   // SYNC_C

    if (tid < 32) {    // gate math: thread = b*4 + d'
      const int b = tid >> 2, dd = tid & 3;
      float gi = gv[b * 16 + dd];
      float gf = gv[b * 16 + 4 + dd];
      float gg = gv[b * 16 + 8 + dd];
      float go = gv[b * 16 + 12 + dd];
      float si = 1.f / (1.f + __expf(-gi));
      float sf = 1.f / (1.f + __expf(-gf));
      float so = 1.f / (1.f + __expf(-go));
      c_reg = sf * c_reg + si * tanhf(gg);
      float hval = so * tanhf(c_reg);
      hs[((long)b * T_ + t) * H_ + d0 + dd] = hval;
      hvals[tid] = hval;
    }
    if (tid < 16) {    // publish: 16 u64 agent stores (one wave-instr)
      const int b = tid >> 1, hf = tid & 1;
      float f0 = hvals[b * 4 + hf * 2];
      float f1 = hvals[b * 4 + hf * 2 + 1];
      u64 pkt = ((u64)__float_as_uint(f1) << 32) | (u64)__float_as_uint(f0);
      const int q = d0 >> 3;
      const int uidx = q * 32 + b * 4 + ((d0 & 7) >> 1) + hf;
      __hip_atomic_store(&hslot[(t & 1) * 2048 + uidx], pkt,
                         __ATOMIC_RELAXED, __HIP_MEMORY_SCOPE_AGENT);
    }
    if (tid == 0)
      __hip_atomic_store(&tags[wg], (unsigned)(t + 1),
                         __ATOMIC_RELEASE, __HIP_MEMORY_SCOPE_AGENT);
  }
}

// ===================== s = tanh(h@W1^T+b1) . w2 + b2 =====================
__global__ __launch_bounds__(256)
void score_kernel(const float* __restrict__ S1, const float* __restrict__ w2,
                  const float* __restrict__ b2, float* __restrict__ scores)
{
  const int lane = threadIdx.x & 63;
  const int row = blockIdx.x * 4 + (threadIdx.x >> 6);
  const float4 a0 = *(const float4*)&S1[(long)row * 512 + lane * 4];
  const float4 a1 = *(const float4*)&S1[(long)row * 512 + 256 + lane * 4];
  const float4 w0 = *(const float4*)&w2[lane * 4];
  const float4 w1 = *(const float4*)&w2[256 + lane * 4];
  float s = a0.x * w0.x + a0.y * w0.y + a0.z * w0.z + a0.w * w0.w
          + a1.x * w1.x + a1.y * w1.y + a1.z * w1.z + a1.w * w1.w;
  #pragma unroll
  for (int off = 32; off; off >>= 1) s += __shfl_xor(s, off);
  if (lane == 0) scores[row] = s + b2[0];
}

// ============= softmax (global max) + cumulative context =============
__global__ __launch_bounds__(256)
void attn_ctx_kernel(const float* __restrict__ scores,
                     const float* __restrict__ hs, float* __restrict__ ctx)
{
  __shared__ float e_lds[T_];
  __shared__ float dinv_lds[T_];
  __shared__ float red[4];
  const int b = blockIdx.x, tid = threadIdx.x;
  float s0 = scores[b * T_ + tid];
  float s1 = scores[b * T_ + 256 + tid];
  float m = fmaxf(s0, s1);
  #pragma unroll
  for (int off = 32; off; off >>= 1) m = fmaxf(m, __shfl_xor(m, off));
  if ((tid & 63) == 0) red[tid >> 6] = m;
  __syncthreads();
  m = fmaxf(fmaxf(red[0], red[1]), fmaxf(red[2], red[3]));
  e_lds[tid] = expf(s0 - m);
  e_lds[tid + 256] = expf(s1 - m);
  __syncthreads();
  if (tid == 0) {
    float run = 0.f;
    for (int t = 0; t < T_; ++t) { run += e_lds[t]; dinv_lds[t] = 1.f / run; }
  }
  __syncthreads();

  float acc0 = 0.f, acc1 = 0.f;
  for (int t0 = 0; t0 < T_; t0 += 8) {
    float hv0[8], hv1[8];
    #pragma unroll
    for (int u = 0; u < 8; ++u) {
      const float* hp = &hs[((long)b * T_ + t0 + u) * H_];
      hv0[u] = hp[tid];
      hv1[u] = hp[tid + 256];
    }
    #pragma unroll
    for (int u = 0; u < 8; ++u) {
      float e = e_lds[t0 + u], di = dinv_lds[t0 + u];
      acc0 += e * hv0[u];
      acc1 += e * hv1[u];
      float* cp = &ctx[((long)b * T_ + t0 + u) * H_];
      cp[tid] = acc0 * di;
      cp[tid + 256] = acc1 * di;
    }
  }
}

// =====================================================================
// Decoder: out[4096][32000] = comb_h(fp16) @ emb_W^T + dec_b
// fp16 MFMA, B split hi/lo in-kernel. 128x128 tile, BK=64, XOR-swizzled
// LDS fragment blocks. grid = 32 m-blocks (fast) x 250 n-blocks.
// =====================================================================
__global__ __launch_bounds__(256)
void dec_gemm(const _Float16* __restrict__ Ah, const float* __restrict__ Bw,
              const float* __restrict__ bias, float* __restrict__ C)
{
  __shared__ _Float16 As [8192];   // blocks (q=0..7, row=0..127): halfidx=(q*128+(row^q))*8
  __shared__ _Float16 Bhi[8192];
  __shared__ _Float16 Blo[8192];
  const int tid = threadIdx.x;
  const int bid = blockIdx.x;
  const int bm = (bid & 31) << 7;
  const int bn = (bid >> 5) << 7;
  const int wv = tid >> 6, l = tid & 63;
  const int mh = wv & 1, nh = wv >> 1;

  f32x4 acc[4][4];
  #pragma unroll
  for (int i = 0; i < 4; ++i)
    #pragma unroll
    for (int j = 0; j < 4; ++j) acc[i][j] = (f32x4){0.f, 0.f, 0.f, 0.f};

  for (int k0 = 0; k0 < 512; k0 += 64) {
    __syncthreads();
    // stage A (fp16 source): 4 x 16B per thread
    #pragma unroll
    for (int p = 0; p < 4; ++p) {
      const int idx = p * 256 + tid;
      const int row = idx >> 3, q = idx & 7;
      f16x8 av = *(const f16x8*)&Ah[(long)(bm + row) * 512 + k0 + q * 8];
      *(f16x8*)&As[(q * 128 + (row ^ q)) * 8] = av;
    }
    // stage B (fp32 source, split): 8 x 16B per thread
    #pragma unroll
    for (int p = 0; p < 8; ++p) {
      const int idx = p * 256 + tid;
      const int row = idx >> 4, qf = idx & 15;
      float4 bv = *(const float4*)&Bw[(long)(bn + row) * 512 + k0 + qf * 4];
      const int q = qf >> 1, hb = qf & 1;
      const int base = (q * 128 + (row ^ q)) * 8 + hb * 4;
      _Float16 h0 = (_Float16)bv.x, h1 = (_Float16)bv.y,
               h2 = (_Float16)bv.z, h3 = (_Float16)bv.w;
      *(unsigned*)&Bhi[base]     = pack2h(h0, h1);
      *(unsigned*)&Bhi[base + 2] = pack2h(h2, h3);
      *(unsigned*)&Blo[base]     = pack2h((_Float16)(bv.x - (float)h0), (_Float16)(bv.y - (float)h1));
      *(unsigned*)&Blo[base + 2] = pack2h((_Float16)(bv.z - (float)h2), (_Float16)(bv.w - (float)h3));
    }
    __syncthreads();

    #pragma unroll
    for (int kt2 = 0; kt2 < 2; ++kt2) {
      const int q = kt2 * 4 + (l >> 4);
      f16x8 af[4], bh[4], bl[4];
      #pragma unroll
      for (int mi = 0; mi < 4; ++mi) {
        const int row = mh * 64 + mi * 16 + (l & 15);
        af[mi] = *(f16x8*)&As[(q * 128 + (row ^ (q & 7))) * 8];
      }
      #pragma unroll
      for (int ni = 0; ni < 4; ++ni) {
        const int row = nh * 64 + ni * 16 + (l & 15);
        bh[ni] = *(f16x8*)&Bhi[(q * 128 + (row ^ (q & 7))) * 8];
        bl[ni] = *(f16x8*)&Blo[(q * 128 + (row ^ (q & 7))) * 8];
      }
      #pragma unroll
      for (int mi = 0; mi < 4; ++mi)
        #pragma unroll
        for (int ni = 0; ni < 4; ++ni) {
          acc[mi][ni] = __builtin_amdgcn_mfma_f32_16x16x32_f16(af[mi], bh[ni], acc[mi][ni], 0, 0, 0);
          acc[mi][ni] = __builtin_amdgcn_mfma_f32_16x16x32_f16(af[mi], bl[ni], acc[mi][ni], 0, 0, 0);
        }
    }
  }

  #pragma unroll
  for (int ni = 0; ni < 4; ++ni) {
    const int n = bn + nh * 64 + ni * 16 + (l & 15);
    const float bv = bias[n];
    #pragma unroll
    for (int mi = 0; mi < 4; ++mi) {
      #pragma unroll
      for (int r = 0; r < 4; ++r) {
        const int m = bm + mh * 64 + mi * 16 + (l >> 4) * 4 + r;
        C[(long)m * V_ + n] = acc[mi][ni][r] + bv;
      }
    }
  }
}

// =====================================================================
extern "C" void kernel_launch(void* const* d_in, const int* in_sizes, int n_in,
                              void* d_out, int out_size, void* d_ws, size_t ws_size,
                              hipStream_t stream)
{
  const int*   src      = (const int*)  d_in[0];
  const float* emb_W    = (const float*)d_in[1];
  const float* W_ih     = (const float*)d_in[2];
  const float* W_hh     = (const float*)d_in[3];
  const float* b_ih     = (const float*)d_in[4];
  const float* b_hh     = (const float*)d_in[5];
  const float* attn1_W  = (const float*)d_in[6];
  const float* attn1_b  = (const float*)d_in[7];
  const float* attn2_W  = (const float*)d_in[8];
  const float* attn2_b  = (const float*)d_in[9];
  const float* concat_W = (const float*)d_in[10];
  const float* concat_b = (const float*)d_in[11];
  const float* dec_b    = (const float*)d_in[12];
  float* out = (float*)d_out;

  // workspace (~42 MB):
  //  [0,33.5M): A_gates; after LSTM reused: S1@0, ctx@8M, comb_h(fp16)@16M
  //  [33.5M, 41.94M): hs ; then scores 16K, tags 1K, hslot 32K
  char* ws = (char*)d_ws;
  float*    A_gates = (float*)(ws);
  float*    S1      = (float*)(ws);
  float*    ctx     = (float*)(ws + (size_t)8388608);
  _Float16* comb_h  = (_Float16*)(ws + (size_t)16777216);
  float*    hs      = (float*)(ws + (size_t)33554432);
  float*    scores  = (float*)(ws + (size_t)41943040);
  unsigned* tags    = (unsigned*)(ws + (size_t)41959424);
  u64*      hslot   = (u64*)(ws + (size_t)41960448);

  dim3 blk(256);
  // 1) A = emb[src] @ W_ih^T + b_ih + b_hh
  gemm128<0><<<dim3(G4H_ / 128, BT_ / 128), blk, 0, stream>>>(
      emb_W, nullptr, W_ih, b_ih, b_hh, src, A_gates, nullptr, BT_, G4H_, 512);
  // 2) persistent LSTM
  hipMemsetAsync(tags, 0, 128 * sizeof(unsigned), stream);
  lstm_mfma<<<dim3(128), blk, 0, stream>>>(A_gates, W_hh, hs, hslot, tags);
  // 3) S1 = tanh(hs @ attn1_W^T + b1)
  gemm128<1><<<dim3(512 / 128, BT_ / 128), blk, 0, stream>>>(
      hs, nullptr, attn1_W, attn1_b, nullptr, nullptr, S1, nullptr, BT_, 512, 512);
  // 4) scores
  score_kernel<<<dim3(BT_ / 4), blk, 0, stream>>>(S1, attn2_W, attn2_b, scores);
  // 5) softmax-cumsum context
  attn_ctx_kernel<<<dim3(B_), blk, 0, stream>>>(scores, hs, ctx);
  // 6) comb = tanh([ctx|hs] @ concat_W^T + bc) -> fp16
  gemm128<2><<<dim3(512 / 128, BT_ / 128), blk, 0, stream>>>(
      ctx, hs, concat_W, concat_b, nullptr, nullptr, nullptr, comb_h, BT_, 512, 1024);
  // 7) logits = comb_h @ emb_W^T + dec_b   (fp16 MFMA, B hi/lo split)
  dec_gemm<<<dim3(32 * 250), blk, 0, stream>>>(comb_h, emb_W, dec_b, out);
}

// Round 3
// 2650.311 us; speedup vs baseline: 3.5441x; 3.5441x over previous
//
#include <hip/hip_runtime.h>
#include <hip/hip_bf16.h>
#include <stdint.h>

typedef unsigned long long u64;
typedef _Float16 f16x8 __attribute__((ext_vector_type(8)));
typedef float f32x4 __attribute__((ext_vector_type(4)));

#define V_   32000
#define D_   512
#define H_   512
#define B_   8
#define T_   512
#define BT_  4096
#define G4H_ 2048

static __device__ inline unsigned pack2h(_Float16 a, _Float16 b) {
  union { _Float16 h[2]; unsigned u; } p;
  p.h[0] = a; p.h[1] = b;
  return p.u;
}

// =====================================================================
// Generic 128x128-tile fp32 GEMM:  C = act(A @ B^T + bias)
//   MODE 0: A = emb_W[src[m]],  B=W_ih,     bias=b_ih+b_hh,        N=2048,K=512
//   MODE 1: A = hs,             B=attn1_W,  bias=attn1_b, tanh,    N=512, K=512
//   MODE 2: A = [ctx | hs],     B=concat_W, bias=concat_b, tanh -> fp16 out
// =====================================================================
template<int MODE>
__global__ __launch_bounds__(256)
void gemm128(const float* __restrict__ A1, const float* __restrict__ A2,
             const float* __restrict__ Bm, const float* __restrict__ bias,
             const float* __restrict__ bias2, const int* __restrict__ src,
             float* __restrict__ C, _Float16* __restrict__ Ch,
             int M, int N, int K)
{
  __shared__ float As[16][132];
  __shared__ float Bs[16][132];
  const int tid = threadIdx.x;
  const int bm = blockIdx.y * 128, bn = blockIdx.x * 128;
  const int tx = tid & 15, ty = tid >> 4;
  const int lr = tid >> 2, lk4 = tid & 3;

  int ga0 = 0, ga1 = 0;
  if constexpr (MODE == 0) { ga0 = src[bm + lr]; ga1 = src[bm + lr + 64]; }

  float acc[8][8];
  #pragma unroll
  for (int i = 0; i < 8; ++i)
    #pragma unroll
    for (int j = 0; j < 8; ++j) acc[i][j] = 0.f;

  for (int k0 = 0; k0 < K; k0 += 16) {
    const int ak = k0 + 4 * lk4;
    float4 av0, av1, bv0, bv1;
    if constexpr (MODE == 0) {
      av0 = *(const float4*)&A1[(long)ga0 * 512 + ak];
      av1 = *(const float4*)&A1[(long)ga1 * 512 + ak];
    } else if constexpr (MODE == 2) {
      if (ak < 512) {
        av0 = *(const float4*)&A1[(long)(bm + lr) * 512 + ak];
        av1 = *(const float4*)&A1[(long)(bm + lr + 64) * 512 + ak];
      } else {
        av0 = *(const float4*)&A2[(long)(bm + lr) * 512 + (ak - 512)];
        av1 = *(const float4*)&A2[(long)(bm + lr + 64) * 512 + (ak - 512)];
      }
    } else {
      av0 = *(const float4*)&A1[(long)(bm + lr) * K + ak];
      av1 = *(const float4*)&A1[(long)(bm + lr + 64) * K + ak];
    }
    bv0 = *(const float4*)&Bm[(long)(bn + lr) * K + ak];
    bv1 = *(const float4*)&Bm[(long)(bn + lr + 64) * K + ak];

    __syncthreads();
    As[4*lk4+0][lr]    = av0.x; As[4*lk4+1][lr]    = av0.y;
    As[4*lk4+2][lr]    = av0.z; As[4*lk4+3][lr]    = av0.w;
    As[4*lk4+0][lr+64] = av1.x; As[4*lk4+1][lr+64] = av1.y;
    As[4*lk4+2][lr+64] = av1.z; As[4*lk4+3][lr+64] = av1.w;
    Bs[4*lk4+0][lr]    = bv0.x; Bs[4*lk4+1][lr]    = bv0.y;
    Bs[4*lk4+2][lr]    = bv0.z; Bs[4*lk4+3][lr]    = bv0.w;
    Bs[4*lk4+0][lr+64] = bv1.x; Bs[4*lk4+1][lr+64] = bv1.y;
    Bs[4*lk4+2][lr+64] = bv1.z; Bs[4*lk4+3][lr+64] = bv1.w;
    __syncthreads();

    #pragma unroll
    for (int kk = 0; kk < 16; ++kk) {
      float4 a0 = *(float4*)&As[kk][ty * 8];
      float4 a1 = *(float4*)&As[kk][ty * 8 + 4];
      float4 b0 = *(float4*)&Bs[kk][tx * 4];
      float4 b1 = *(float4*)&Bs[kk][64 + tx * 4];
      float a[8] = {a0.x, a0.y, a0.z, a0.w, a1.x, a1.y, a1.z, a1.w};
      float b[8] = {b0.x, b0.y, b0.z, b0.w, b1.x, b1.y, b1.z, b1.w};
      #pragma unroll
      for (int i = 0; i < 8; ++i)
        #pragma unroll
        for (int j = 0; j < 8; ++j) acc[i][j] += a[i] * b[j];
    }
  }

  #pragma unroll
  for (int i = 0; i < 8; ++i) {
    const int m = bm + ty * 8 + i;
    #pragma unroll
    for (int half = 0; half < 2; ++half) {
      const int n0 = bn + half * 64 + tx * 4;
      float vv[4];
      #pragma unroll
      for (int j = 0; j < 4; ++j) {
        float x = acc[i][half * 4 + j];
        x += bias[n0 + j];
        if constexpr (MODE == 0) x += bias2[n0 + j];
        if constexpr (MODE == 1 || MODE == 2) x = tanhf(x);
        vv[j] = x;
      }
      if constexpr (MODE == 2) {
        #pragma unroll
        for (int j = 0; j < 4; ++j) Ch[(long)m * 512 + n0 + j] = (_Float16)vv[j];
      } else {
        *(float4*)&C[(long)m * N + n0] = *(float4*)vv;
      }
    }
  }
}

// =====================================================================
// Persistent LSTM, batch-parallel groups.
// 256 WGs self-organize via ticket counter into 8 groups of exactly 32;
// group x owns batch x; WG slot s owns h-dims [16s,16s+16) (64 gate rows).
// W_hh slice in 128 fp32 VGPRs/thread. One-trip tagged u64 packets
// (tag = t+1 | float bits), relaxed agent atomics, no fences.
// Per step: spin(2 pkts/thread) -> barrier -> fp32 dot -> barrier ->
// reduce+gates+publish (wave 0).
// =====================================================================
__global__ __launch_bounds__(256, 1)
void lstm_groups(const float* __restrict__ A, const float* __restrict__ W_hh,
                 float* __restrict__ hs, u64* __restrict__ hbuf,
                 int* __restrict__ cnt)
{
  __shared__ float h_lds[4 * 132];    // q-blocks padded: block q at q*132
  __shared__ float partial[64 * 5];   // [row][q], stride 5
  __shared__ float gv[64];            // raw gate values (rows g*16+dloc)
  __shared__ int s_slot;

  const int tid = threadIdx.x;
  if (tid == 0) s_slot = atomicAdd(cnt, 1);
  for (int i = tid; i < 4 * 132; i += 256) h_lds[i] = 0.f;
  __syncthreads();
  const int slot = s_slot;
  const int x = slot >> 5;          // group / batch
  const int s = slot & 31;          // slot in group
  const int base_d = 16 * s;

  // thread mapping for dot: row r (of 64 gate rows), k-chunk q (of 4 x 128)
  const int q = tid & 3, r = tid >> 2;
  const int grow = (r >> 4) * 512 + base_d + (r & 15);   // global gate row

  // W_hh slice in registers: 128 k-values = 32 float4
  float4 w4[32];
  #pragma unroll
  for (int i = 0; i < 32; ++i)
    w4[i] = *(const float4*)&W_hh[(long)grow * 512 + q * 128 + 4 * i];

  u64* hb = hbuf + (size_t)x * 512;
  const int da = 2 * tid, db = 2 * tid + 1;
  const int la = (da >> 7) * 132 + (da & 127);
  const int lb = (db >> 7) * 132 + (db & 127);

  float c_reg = 0.f;
  __syncthreads();

  for (int t = 0; t < T_; ++t) {
    // prefetch this step's input-gate contribution (used in reduce phase)
    float a_val = 0.f;
    if (tid < 64)
      a_val = A[(size_t)(x * T_ + t) * G4H_ + (tid >> 4) * 512 + base_d + (tid & 15)];

    if (t > 0) {
      // one-trip spin: data is the flag (tag == t)
      const unsigned want = (unsigned)t;
      bool g0 = false, g1 = false;
      int guard = 0;
      while (!(g0 && g1)) {
        if (!g0) {
          u64 p = __hip_atomic_load(&hb[da], __ATOMIC_RELAXED, __HIP_MEMORY_SCOPE_AGENT);
          if ((unsigned)(p >> 32) == want) { h_lds[la] = __uint_as_float((unsigned)p); g0 = true; }
        }
        if (!g1) {
          u64 p = __hip_atomic_load(&hb[db], __ATOMIC_RELAXED, __HIP_MEMORY_SCOPE_AGENT);
          if ((unsigned)(p >> 32) == want) { h_lds[lb] = __uint_as_float((unsigned)p); g1 = true; }
        }
        if (!(g0 && g1)) {
          __builtin_amdgcn_s_sleep(1);
          if (++guard > (1 << 22)) break;   // hang-breaker (fails loud, not silent)
        }
      }
    }
    __syncthreads();   // h[t-1] staged

    // fp32 dot: gate_row r, k in [q*128, q*128+128)
    float ax = 0.f, ay = 0.f, az = 0.f, aw = 0.f;
    const float4* h4 = (const float4*)&h_lds[q * 132];
    #pragma unroll
    for (int i = 0; i < 32; ++i) {
      float4 hv = h4[i];
      ax += w4[i].x * hv.x; ay += w4[i].y * hv.y;
      az += w4[i].z * hv.z; aw += w4[i].w * hv.w;
    }
    partial[r * 5 + q] = (ax + ay) + (az + aw);
    __syncthreads();   // partials ready

    if (tid < 64) {    // reduce 4 k-chunks + input part -> raw gate
      float g = a_val;
      #pragma unroll
      for (int qq = 0; qq < 4; ++qq) g += partial[tid * 5 + qq];
      gv[tid] = g;
    }
    if (tid < 16) {    // gate math for dim base_d+tid (same wave as reduce)
      float gi = gv[tid];
      float gf = gv[16 + tid];
      float gg = gv[32 + tid];
      float go = gv[48 + tid];
      float si = 1.f / (1.f + __expf(-gi));
      float sf = 1.f / (1.f + __expf(-gf));
      float so = 1.f / (1.f + __expf(-go));
      c_reg = sf * c_reg + si * tanhf(gg);
      float hval = so * tanhf(c_reg);
      hs[(size_t)(x * T_ + t) * H_ + base_d + tid] = hval;
      u64 pkt = ((u64)(unsigned)(t + 1) << 32) | (u64)__float_as_uint(hval);
      __hip_atomic_store(&hb[base_d + tid], pkt, __ATOMIC_RELAXED,
                         __HIP_MEMORY_SCOPE_AGENT);
    }
    __syncthreads();
  }
}

// ===================== s = tanh(h@W1^T+b1) . w2 + b2 =====================
__global__ __launch_bounds__(256)
void score_kernel(const float* __restrict__ S1, const float* __restrict__ w2,
                  const float* __restrict__ b2, float* __restrict__ scores)
{
  const int lane = threadIdx.x & 63;
  const int row = blockIdx.x * 4 + (threadIdx.x >> 6);
  const float4 a0 = *(const float4*)&S1[(long)row * 512 + lane * 4];
  const float4 a1 = *(const float4*)&S1[(long)row * 512 + 256 + lane * 4];
  const float4 w0 = *(const float4*)&w2[lane * 4];
  const float4 w1 = *(const float4*)&w2[256 + lane * 4];
  float s = a0.x * w0.x + a0.y * w0.y + a0.z * w0.z + a0.w * w0.w
          + a1.x * w1.x + a1.y * w1.y + a1.z * w1.z + a1.w * w1.w;
  #pragma unroll
  for (int off = 32; off; off >>= 1) s += __shfl_xor(s, off);
  if (lane == 0) scores[row] = s + b2[0];
}

// ============= softmax (global max) + cumulative context =============
__global__ __launch_bounds__(256)
void attn_ctx_kernel(const float* __restrict__ scores,
                     const float* __restrict__ hs, float* __restrict__ ctx)
{
  __shared__ float e_lds[T_];
  __shared__ float dinv_lds[T_];
  __shared__ float red[4];
  const int b = blockIdx.x, tid = threadIdx.x;
  float s0 = scores[b * T_ + tid];
  float s1 = scores[b * T_ + 256 + tid];
  float m = fmaxf(s0, s1);
  #pragma unroll
  for (int off = 32; off; off >>= 1) m = fmaxf(m, __shfl_xor(m, off));
  if ((tid & 63) == 0) red[tid >> 6] = m;
  __syncthreads();
  m = fmaxf(fmaxf(red[0], red[1]), fmaxf(red[2], red[3]));
  e_lds[tid] = expf(s0 - m);
  e_lds[tid + 256] = expf(s1 - m);
  __syncthreads();
  if (tid == 0) {
    float run = 0.f;
    for (int t = 0; t < T_; ++t) { run += e_lds[t]; dinv_lds[t] = 1.f / run; }
  }
  __syncthreads();

  float acc0 = 0.f, acc1 = 0.f;
  for (int t0 = 0; t0 < T_; t0 += 8) {
    float hv0[8], hv1[8];
    #pragma unroll
    for (int u = 0; u < 8; ++u) {
      const float* hp = &hs[((long)b * T_ + t0 + u) * H_];
      hv0[u] = hp[tid];
      hv1[u] = hp[tid + 256];
    }
    #pragma unroll
    for (int u = 0; u < 8; ++u) {
      float e = e_lds[t0 + u], di = dinv_lds[t0 + u];
      acc0 += e * hv0[u];
      acc1 += e * hv1[u];
      float* cp = &ctx[((long)b * T_ + t0 + u) * H_];
      cp[tid] = acc0 * di;
      cp[tid + 256] = acc1 * di;
    }
  }
}

// =====================================================================
// Decoder: out[4096][32000] = comb_h(fp16) @ emb_W^T + dec_b
// fp16 MFMA, B split hi/lo in-kernel. 128x128 tile, BK=64, XOR-swizzled
// LDS fragment blocks. grid = 32 m-blocks (fast) x 250 n-blocks.
// =====================================================================
__global__ __launch_bounds__(256)
void dec_gemm(const _Float16* __restrict__ Ah, const float* __restrict__ Bw,
              const float* __restrict__ bias, float* __restrict__ C)
{
  __shared__ _Float16 As [8192];
  __shared__ _Float16 Bhi[8192];
  __shared__ _Float16 Blo[8192];
  const int tid = threadIdx.x;
  const int bid = blockIdx.x;
  const int bm = (bid & 31) << 7;
  const int bn = (bid >> 5) << 7;
  const int wv = tid >> 6, l = tid & 63;
  const int mh = wv & 1, nh = wv >> 1;

  f32x4 acc[4][4];
  #pragma unroll
  for (int i = 0; i < 4; ++i)
    #pragma unroll
    for (int j = 0; j < 4; ++j) acc[i][j] = (f32x4){0.f, 0.f, 0.f, 0.f};

  for (int k0 = 0; k0 < 512; k0 += 64) {
    __syncthreads();
    #pragma unroll
    for (int p = 0; p < 4; ++p) {
      const int idx = p * 256 + tid;
      const int row = idx >> 3, q = idx & 7;
      f16x8 av = *(const f16x8*)&Ah[(long)(bm + row) * 512 + k0 + q * 8];
      *(f16x8*)&As[(q * 128 + (row ^ q)) * 8] = av;
    }
    #pragma unroll
    for (int p = 0; p < 8; ++p) {
      const int idx = p * 256 + tid;
      const int row = idx >> 4, qf = idx & 15;
      float4 bv = *(const float4*)&Bw[(long)(bn + row) * 512 + k0 + qf * 4];
      const int q = qf >> 1, hb = qf & 1;
      const int base = (q * 128 + (row ^ q)) * 8 + hb * 4;
      _Float16 h0 = (_Float16)bv.x, h1 = (_Float16)bv.y,
               h2 = (_Float16)bv.z, h3 = (_Float16)bv.w;
      *(unsigned*)&Bhi[base]     = pack2h(h0, h1);
      *(unsigned*)&Bhi[base + 2] = pack2h(h2, h3);
      *(unsigned*)&Blo[base]     = pack2h((_Float16)(bv.x - (float)h0), (_Float16)(bv.y - (float)h1));
      *(unsigned*)&Blo[base + 2] = pack2h((_Float16)(bv.z - (float)h2), (_Float16)(bv.w - (float)h3));
    }
    __syncthreads();

    #pragma unroll
    for (int kt2 = 0; kt2 < 2; ++kt2) {
      const int q = kt2 * 4 + (l >> 4);
      f16x8 af[4], bh[4], bl[4];
      #pragma unroll
      for (int mi = 0; mi < 4; ++mi) {
        const int row = mh * 64 + mi * 16 + (l & 15);
        af[mi] = *(f16x8*)&As[(q * 128 + (row ^ (q & 7))) * 8];
      }
      #pragma unroll
      for (int ni = 0; ni < 4; ++ni) {
        const int row = nh * 64 + ni * 16 + (l & 15);
        bh[ni] = *(f16x8*)&Bhi[(q * 128 + (row ^ (q & 7))) * 8];
        bl[ni] = *(f16x8*)&Blo[(q * 128 + (row ^ (q & 7))) * 8];
      }
      #pragma unroll
      for (int mi = 0; mi < 4; ++mi)
        #pragma unroll
        for (int ni = 0; ni < 4; ++ni) {
          acc[mi][ni] = __builtin_amdgcn_mfma_f32_16x16x32_f16(af[mi], bh[ni], acc[mi][ni], 0, 0, 0);
          acc[mi][ni] = __builtin_amdgcn_mfma_f32_16x16x32_f16(af[mi], bl[ni], acc[mi][ni], 0, 0, 0);
        }
    }
  }

  #pragma unroll
  for (int ni = 0; ni < 4; ++ni) {
    const int n = bn + nh * 64 + ni * 16 + (l & 15);
    const float bv = bias[n];
    #pragma unroll
    for (int mi = 0; mi < 4; ++mi) {
      #pragma unroll
      for (int r = 0; r < 4; ++r) {
        const int m = bm + mh * 64 + mi * 16 + (l >> 4) * 4 + r;
        C[(long)m * V_ + n] = acc[mi][ni][r] + bv;
      }
    }
  }
}

// =====================================================================
extern "C" void kernel_launch(void* const* d_in, const int* in_sizes, int n_in,
                              void* d_out, int out_size, void* d_ws, size_t ws_size,
                              hipStream_t stream)
{
  const int*   src      = (const int*)  d_in[0];
  const float* emb_W    = (const float*)d_in[1];
  const float* W_ih     = (const float*)d_in[2];
  const float* W_hh     = (const float*)d_in[3];
  const float* b_ih     = (const float*)d_in[4];
  const float* b_hh     = (const float*)d_in[5];
  const float* attn1_W  = (const float*)d_in[6];
  const float* attn1_b  = (const float*)d_in[7];
  const float* attn2_W  = (const float*)d_in[8];
  const float* attn2_b  = (const float*)d_in[9];
  const float* concat_W = (const float*)d_in[10];
  const float* concat_b = (const float*)d_in[11];
  const float* dec_b    = (const float*)d_in[12];
  float* out = (float*)d_out;

  // workspace (~42 MB):
  //  [0,33.5M): A_gates; after LSTM reused: S1@0, ctx@8M, comb_h(fp16)@16M
  //  [33.5M, 41.94M): hs ; then scores 16K, hbuf 32K, cnt 4B
  char* ws = (char*)d_ws;
  float*    A_gates = (float*)(ws);
  float*    S1      = (float*)(ws);
  float*    ctx     = (float*)(ws + (size_t)8388608);
  _Float16* comb_h  = (_Float16*)(ws + (size_t)16777216);
  float*    hs      = (float*)(ws + (size_t)33554432);
  float*    scores  = (float*)(ws + (size_t)41943040);
  u64*      hbuf    = (u64*)(ws + (size_t)41959424);
  int*      cnt     = (int*)(ws + (size_t)41992192);

  dim3 blk(256);
  // 1) A = emb[src] @ W_ih^T + b_ih + b_hh
  gemm128<0><<<dim3(G4H_ / 128, BT_ / 128), blk, 0, stream>>>(
      emb_W, nullptr, W_ih, b_ih, b_hh, src, A_gates, nullptr, BT_, G4H_, 512);
  // 2) persistent batch-parallel LSTM (hbuf needs no clear: tag exact-match)
  hipMemsetAsync(cnt, 0, sizeof(int), stream);
  lstm_groups<<<dim3(256), blk, 0, stream>>>(A_gates, W_hh, hs, hbuf, cnt);
  // 3) S1 = tanh(hs @ attn1_W^T + b1)
  gemm128<1><<<dim3(512 / 128, BT_ / 128), blk, 0, stream>>>(
      hs, nullptr, attn1_W, attn1_b, nullptr, nullptr, S1, nullptr, BT_, 512, 512);
  // 4) scores
  score_kernel<<<dim3(BT_ / 4), blk, 0, stream>>>(S1, attn2_W, attn2_b, scores);
  // 5) softmax-cumsum context
  attn_ctx_kernel<<<dim3(B_), blk, 0, stream>>>(scores, hs, ctx);
  // 6) comb = tanh([ctx|hs] @ concat_W^T + bc) -> fp16
  gemm128<2><<<dim3(512 / 128, BT_ / 128), blk, 0, stream>>>(
      ctx, hs, concat_W, concat_b, nullptr, nullptr, nullptr, comb_h, BT_, 512, 1024);
  // 7) logits = comb_h @ emb_W^T + dec_b   (fp16 MFMA, B hi/lo split)
  dec_gemm<<<dim3(32 * 250), blk, 0, stream>>>(comb_h, emb_W, dec_b, out);
}